// Round 9
// baseline (198.653 us; speedup 1.0000x reference)
//
#include <hip/hip_runtime.h>

#define Bz 4
#define Nn 1024
#define Dd 1024
#define Hh 16
#define HD 64
#define SCALE 0.125f
#define LN_EPS 1e-5f

typedef __attribute__((ext_vector_type(8))) __bf16 bf16x8;
typedef __attribute__((ext_vector_type(4))) float f32x4;
typedef __attribute__((ext_vector_type(4))) unsigned int uint4v;

static __device__ inline unsigned short f2bf(float f) {
    unsigned int u = __float_as_uint(f);
    u += 0x7fffu + ((u >> 16) & 1u);   // round-to-nearest-even
    return (unsigned short)(u >> 16);
}

static __device__ inline bf16x8 ldfrag(const unsigned short* p) {
    return *(const bf16x8*)p;
}

static __device__ __forceinline__ void glds16(const unsigned short* g, unsigned short* l) {
    __builtin_amdgcn_global_load_lds((const __attribute__((address_space(1))) void*)g,
                                     (__attribute__((address_space(3))) void*)l, 16, 0, 0);
}

// ===== prep: LN (blocks 0..4095) + transpose w_qkv (4096..7167) +
//             transpose w_proj (7168..8191), all 256-thread blocks ==========
__global__ __launch_bounds__(256) void prep_kernel(const float* __restrict__ x,
                                                   const float* __restrict__ gamma,
                                                   const float* __restrict__ beta,
                                                   unsigned short* __restrict__ xn,
                                                   const float* __restrict__ w_qkv,
                                                   unsigned short* __restrict__ wqkvT,
                                                   const float* __restrict__ w_proj,
                                                   unsigned short* __restrict__ wprojT) {
    __shared__ float tile[32][33];
    int blk = blockIdx.x;
    int tid = threadIdx.x;

    if (blk < 4096) {
        // -------- LayerNorm row --------
        const float* xr = x + (size_t)blk * Dd;
        float4 v = ((const float4*)xr)[tid];
        float s = v.x + v.y + v.z + v.w;
        float ss = v.x * v.x + v.y * v.y + v.z * v.z + v.w * v.w;
        for (int o = 32; o > 0; o >>= 1) {
            s += __shfl_down(s, o);
            ss += __shfl_down(ss, o);
        }
        float* red = &tile[0][0];
        int wid = tid >> 6;
        if ((tid & 63) == 0) { red[wid * 2] = s; red[wid * 2 + 1] = ss; }
        __syncthreads();
        float tot = red[0] + red[2] + red[4] + red[6];
        float tot2 = red[1] + red[3] + red[5] + red[7];
        float mu = tot * (1.0f / Dd);
        float var = tot2 * (1.0f / Dd) - mu * mu;
        float inv = rsqrtf(var + LN_EPS);
        float4 g = ((const float4*)gamma)[tid];
        float4 b = ((const float4*)beta)[tid];
        ushort4 o4;
        o4.x = f2bf((v.x - mu) * inv * g.x + b.x);
        o4.y = f2bf((v.y - mu) * inv * g.y + b.y);
        o4.z = f2bf((v.z - mu) * inv * g.z + b.z);
        o4.w = f2bf((v.w - mu) * inv * g.w + b.w);
        ((ushort4*)(xn + (size_t)blk * Dd))[tid] = o4;
    } else {
        // -------- weight transpose fp32 [rows][cols] -> bf16 [cols][rows] ----
        const float* in;
        unsigned short* out;
        int cols, c0, r0;
        if (blk < 7168) {
            int idx = blk - 4096;            // 96 x-tiles, 32 y-tiles
            in = w_qkv; out = wqkvT; cols = 3072;
            c0 = (idx % 96) * 32; r0 = (idx / 96) * 32;
        } else {
            int idx = blk - 7168;            // 32 x 32 tiles
            in = w_proj; out = wprojT; cols = 1024;
            c0 = (idx % 32) * 32; r0 = (idx / 32) * 32;
        }
        int tx = tid & 31, ty = tid >> 5;    // 32 x 8
        #pragma unroll
        for (int i = 0; i < 32; i += 8)
            tile[ty + i][tx] = in[(size_t)(r0 + ty + i) * cols + c0 + tx];
        __syncthreads();
        #pragma unroll
        for (int i = 0; i < 32; i += 8)
            out[(size_t)(c0 + ty + i) * 1024 + r0 + tx] = f2bf(tile[tx][ty + i]);
    }
}

// ========== GEMM body: 128x128 tile, BK=64 (32 MFMA / barrier pair) ========
// LDS [128 rows][64 shorts]; chunk (16B) slot swizzle: slot s holds global
// chunk (s - (row>>1))&7 -> fragment b128 reads rotate start bank per row pair.

// -------- QKV GEMM: xn[4096][1024] @ wqkvT[3072][1024] -> q/k/vt scatter ----
__global__ __launch_bounds__(256) void gemm_qkv(const unsigned short* __restrict__ A,
                                                const unsigned short* __restrict__ Bt,
                                                unsigned short* __restrict__ qb,
                                                unsigned short* __restrict__ kb,
                                                unsigned short* __restrict__ vtb) {
    __shared__ unsigned short sA[8192], sB[8192];
    int tid = threadIdx.x;
    int w = tid >> 6, lane = tid & 63, lrow = lane & 15, quad = lane >> 4;
    int wm = w >> 1, wn = w & 1;
    int rowbase = blockIdx.y * 128;
    int colbase = blockIdx.x * 128;

    int srow = tid >> 3;
    int gch = ((tid & 7) - (srow >> 1)) & 7;
    const unsigned short* gA = A + (size_t)(rowbase + srow) * 1024 + gch * 8;
    const unsigned short* gB = Bt + (size_t)(colbase + srow) * 1024 + gch * 8;
    unsigned short* lA = sA + w * 512;
    unsigned short* lB = sB + w * 512;

    int bs0 = ((quad + (lrow >> 1)) & 7) * 8;
    int bs1 = ((4 + quad + (lrow >> 1)) & 7) * 8;
    const unsigned short* fa = sA + (wm * 64 + lrow) * 64;
    const unsigned short* fb = sB + (wn * 64 + lrow) * 64;

    f32x4 acc[4][4];
    #pragma unroll
    for (int i = 0; i < 4; i++)
        #pragma unroll
        for (int j = 0; j < 4; j++)
            acc[i][j] = (f32x4){0.f, 0.f, 0.f, 0.f};

    for (int k0 = 0; k0 < 1024; k0 += 64) {
        __syncthreads();
        #pragma unroll
        for (int c = 0; c < 4; c++) {
            glds16(gA + (size_t)c * 32768 + k0, lA + c * 2048);
            glds16(gB + (size_t)c * 32768 + k0, lB + c * 2048);
        }
        __syncthreads();
        #pragma unroll
        for (int s = 0; s < 2; s++) {
            int bo = s ? bs1 : bs0;
            bf16x8 a[4], b[4];
            #pragma unroll
            for (int i = 0; i < 4; i++) a[i] = *(const bf16x8*)(fa + i * 1024 + bo);
            #pragma unroll
            for (int j = 0; j < 4; j++) b[j] = *(const bf16x8*)(fb + j * 1024 + bo);
            #pragma unroll
            for (int i = 0; i < 4; i++)
                #pragma unroll
                for (int j = 0; j < 4; j++)
                    acc[i][j] = __builtin_amdgcn_mfma_f32_16x16x32_bf16(a[i], b[j], acc[i][j], 0, 0, 0);
        }
    }

    if (colbase < 2048) {
        // q/k columns: e-contiguous scalar stores
        #pragma unroll
        for (int j = 0; j < 4; j++) {
            int col = colbase + wn * 64 + j * 16 + lrow;
            int s = col >> 10, rem = col & 1023;
            int h = rem >> 6, e = rem & 63;
            unsigned short* dst = (s == 0) ? qb : kb;
            #pragma unroll
            for (int i = 0; i < 4; i++) {
                #pragma unroll
                for (int r = 0; r < 4; r++) {
                    int R = rowbase + wm * 64 + i * 16 + quad * 4 + r;
                    int bb = R >> 10, n = R & 1023;
                    dst[(((size_t)(bb * Hh + h)) * Nn + n) * HD + e] = f2bf(acc[i][j][r]);
                }
            }
        }
    } else {
        // v columns: transpose 64x64 wave tile through LDS -> b64 n-contiguous
        int bb = rowbase >> 10;
        int nbase = (rowbase & 1023) + wm * 64;
        unsigned short* sc = sA + w * 2048;      // per-wave scratch [16][68]
        int er = lane >> 2, nc = lane & 3;
        #pragma unroll
        for (int j = 0; j < 4; j++) {
            __syncthreads();
            int ebase = colbase + wn * 64 + j * 16 - 2048;
            int h = ebase >> 6, e0 = ebase & 63;
            #pragma unroll
            for (int i = 0; i < 4; i++) {
                uint2 pk;
                pk.x = (unsigned)f2bf(acc[i][j][0]) | ((unsigned)f2bf(acc[i][j][1]) << 16);
                pk.y = (unsigned)f2bf(acc[i][j][2]) | ((unsigned)f2bf(acc[i][j][3]) << 16);
                *(uint2*)(sc + lrow * 68 + i * 16 + quad * 4) = pk;
            }
            __syncthreads();
            unsigned short* vrow = vtb + ((size_t)((bb * Hh + h) * HD) + e0 + er) * Nn + nbase;
            #pragma unroll
            for (int c = 0; c < 4; c++) {
                uint2 v = *(const uint2*)(sc + er * 68 + c * 16 + nc * 4);
                *(uint2*)(vrow + c * 16 + nc * 4) = v;
            }
        }
    }
}

// ---- proj GEMM v2 (r12): aout[4096][1024] @ wprojT[1024][1024] + bias + x --
// 512 thr / 8 waves (2M x 4N, 64x32 per wave) => 2 waves/SIMD, 2-phase dbuf
// (stage(t+1) issued BEFORE compute(t), ONE barrier/iter).
__global__ __launch_bounds__(512, 2) void gemm_proj(const unsigned short* __restrict__ A,
                                                    const unsigned short* __restrict__ Bt,
                                                    const float* __restrict__ bias,
                                                    const float* __restrict__ x,
                                                    float* __restrict__ out) {
    __shared__ unsigned short sA[2][8192], sB[2][8192];
    int tid = threadIdx.x;
    int w = tid >> 6, lane = tid & 63, lrow = lane & 15, quad = lane >> 4;
    int wm = w >> 2, wn = w & 3;           // 2 x 4 wave grid
    int rowbase = blockIdx.y * 128;
    int colbase = blockIdx.x * 128;

    // staging: 512 threads x 2 chunks cover each 128x64 tile (1024 chunks)
    int srow = tid >> 3;                   // 0..63 (rows 0-63; +64 for 2nd chunk)
    int gch = ((tid & 7) - (srow >> 1)) & 7;   // same swizzle for row and row+64
    const unsigned short* gA = A + (size_t)(rowbase + srow) * 1024 + gch * 8;
    const unsigned short* gB = Bt + (size_t)(colbase + srow) * 1024 + gch * 8;

    int bs0 = ((quad + (lrow >> 1)) & 7) * 8;
    int bs1 = ((4 + quad + (lrow >> 1)) & 7) * 8;

    f32x4 acc[4][2];
    #pragma unroll
    for (int i = 0; i < 4; i++)
        #pragma unroll
        for (int j = 0; j < 2; j++)
            acc[i][j] = (f32x4){0.f, 0.f, 0.f, 0.f};

    // prologue: stage k-tile 0 into buffer 0
    glds16(gA, &sA[0][0] + w * 512);
    glds16(gA + (size_t)64 * 1024, &sA[0][0] + 4096 + w * 512);
    glds16(gB, &sB[0][0] + w * 512);
    glds16(gB + (size_t)64 * 1024, &sB[0][0] + 4096 + w * 512);
    __syncthreads();

    for (int t = 0; t < 16; t++) {
        int cur = t & 1;
        if (t < 15) {
            // issue next k-tile staging BEFORE compute (overlaps with MFMA)
            int k1 = (t + 1) * 64;
            glds16(gA + k1, &sA[cur ^ 1][0] + w * 512);
            glds16(gA + (size_t)64 * 1024 + k1, &sA[cur ^ 1][0] + 4096 + w * 512);
            glds16(gB + k1, &sB[cur ^ 1][0] + w * 512);
            glds16(gB + (size_t)64 * 1024 + k1, &sB[cur ^ 1][0] + 4096 + w * 512);
        }

        const unsigned short* fa = &sA[cur][0] + (wm * 64 + lrow) * 64;
        const unsigned short* fb = &sB[cur][0] + (wn * 32 + lrow) * 64;
        #pragma unroll
        for (int s = 0; s < 2; s++) {
            int bo = s ? bs1 : bs0;
            bf16x8 a[4], b[2];
            #pragma unroll
            for (int i = 0; i < 4; i++) a[i] = *(const bf16x8*)(fa + i * 1024 + bo);
            #pragma unroll
            for (int j = 0; j < 2; j++) b[j] = *(const bf16x8*)(fb + j * 1024 + bo);
            #pragma unroll
            for (int i = 0; i < 4; i++)
                #pragma unroll
                for (int j = 0; j < 2; j++)
                    acc[i][j] = __builtin_amdgcn_mfma_f32_16x16x32_bf16(a[i], b[j], acc[i][j], 0, 0, 0);
        }

        __syncthreads();   // drains staging(t+1); all waves done reading buf[cur]
    }

    #pragma unroll
    for (int j = 0; j < 2; j++) {
        int col = colbase + wn * 32 + j * 16 + lrow;
        float bc = bias[col];
        #pragma unroll
        for (int i = 0; i < 4; i++) {
            #pragma unroll
            for (int r = 0; r < 4; r++) {
                int R = rowbase + wm * 64 + i * 16 + quad * 4 + r;
                out[(size_t)R * 1024 + col] = acc[i][j][r] + bc + x[(size_t)R * 1024 + col];
            }
        }
    }
}

// ============ fused attention v9 (r13): KVBLK=128, 8 iterations ===========
// v8's P-in-register body (K-row pi-permute, bit-identical MFMA order), but
// 128 keys/iter as two 64-key halves => HALF the barriers/drains. Theory:
// per-iteration cost is ~7200cy fixed latency (3 variants at 16 iters all
// ~48us regardless of per-iter work) -> 8 iters should land ~30-36us.
// Sim pipeline: half1's sim prefetched before half0 compute; next-iter
// half0's before half1 compute (register pressure flat at 2x f32x4[4][2]).
// LDS 64KB (2 blocks/CU kept).
#define LOG2E 1.4426950408889634f

#define SIMLOAD(DST, MBASE)                                       \
    _Pragma("unroll")                                             \
    for (int ks = 0; ks < 4; ks++) {                              \
        int koff = ((ks & 1) << 5) | ((ks >> 1) << 2);            \
        DST[ks][0] = *(const float4*)(gS0 + (MBASE) + koff);      \
        DST[ks][1] = *(const float4*)(gS1 + (MBASE) + koff);      \
    }

#define STAGE(BUF, MBASE)                                                                      \
    {                                                                                          \
        unsigned short* dK = &sK[BUF][0];                                                      \
        unsigned short* dV = &sV[BUF][0];                                                      \
        _Pragma("unroll")                                                                      \
        for (int hh = 0; hh < 2; hh++) {                                                       \
            int m = (MBASE) + hh * 64;                                                         \
            glds16(k + (size_t)(m + growA) * HD + cgA * 8, dK + hh * 4096 + w * 512);          \
            glds16(k + (size_t)(m + growB) * HD + cgB * 8, dK + hh * 4096 + 2048 + w * 512);   \
            glds16(vt + (size_t)rowA * Nn + m + cgA * 8, dV + hh * 4096 + w * 512);            \
            glds16(vt + (size_t)rowB * Nn + m + cgB * 8, dV + hh * 4096 + 2048 + w * 512);     \
        }                                                                                      \
    }

#define HALF_COMPUTE(SKC, SVC)                                                                 \
    {                                                                                          \
        uint2 pk[2][4];                                                                        \
        _Pragma("unroll")                                                                      \
        for (int ks = 0; ks < 4; ks++) {                                                       \
            const unsigned short* kr = (SKC) + (ks * 16 + lrow) * 64;                          \
            bf16x8 ak0 = *(const bf16x8*)(kr + bs0 * 8);                                       \
            bf16x8 ak1 = *(const bf16x8*)(kr + bs1 * 8);                                       \
            _Pragma("unroll")                                                                  \
            for (int g = 0; g < 2; g++) {                                                      \
                f32x4 c = (f32x4){0.f, 0.f, 0.f, 0.f};                                         \
                c = __builtin_amdgcn_mfma_f32_16x16x32_bf16(ak0, qf[g][0], c, 0, 0, 0);        \
                c = __builtin_amdgcn_mfma_f32_16x16x32_bf16(ak1, qf[g][1], c, 0, 0, 0);        \
                float e0 = __builtin_amdgcn_exp2f(c1 * c[0] + a2 * sm[ks][g].x);               \
                float e1 = __builtin_amdgcn_exp2f(c1 * c[1] + a2 * sm[ks][g].y);               \
                float e2 = __builtin_amdgcn_exp2f(c1 * c[2] + a2 * sm[ks][g].z);               \
                float e3 = __builtin_amdgcn_exp2f(c1 * c[3] + a2 * sm[ks][g].w);               \
                rsum[g] += (e0 + e1) + (e2 + e3);                                              \
                pk[g][ks].x = (__float_as_uint(e0) >> 16) | (__float_as_uint(e1) & 0xffff0000u); \
                pk[g][ks].y = (__float_as_uint(e2) >> 16) | (__float_as_uint(e3) & 0xffff0000u); \
            }                                                                                  \
        }                                                                                      \
        __builtin_amdgcn_s_setprio(1);                                                         \
        _Pragma("unroll")                                                                      \
        for (int ms = 0; ms < 2; ms++) {                                                       \
            bf16x8 pa[2];                                                                      \
            _Pragma("unroll")                                                                  \
            for (int g = 0; g < 2; g++) {                                                      \
                uint4v u;                                                                      \
                u.x = pk[g][ms].x;  u.y = pk[g][ms].y;                                         \
                u.z = pk[g][ms + 2].x;  u.w = pk[g][ms + 2].y;                                 \
                pa[g] = __builtin_bit_cast(bf16x8, u);                                         \
            }                                                                                  \
            _Pragma("unroll")                                                                  \
            for (int et = 0; et < 4; et++) {                                                   \
                int e = et * 16 + lrow;                                                        \
                int slot = (ms * 4 + quad + (e >> 1)) & 7;                                     \
                bf16x8 vb = *(const bf16x8*)((SVC) + e * 64 + slot * 8);                       \
                _Pragma("unroll")                                                              \
                for (int g = 0; g < 2; g++)                                                    \
                    o[g][et] = __builtin_amdgcn_mfma_f32_16x16x32_bf16(pa[g], vb, o[g][et], 0, 0, 0); \
            }                                                                                  \
        }                                                                                      \
        __builtin_amdgcn_s_setprio(0);                                                         \
    }

__global__ __launch_bounds__(256, 2) void attn_kernel(const unsigned short* __restrict__ qb,
                                                      const unsigned short* __restrict__ kb,
                                                      const unsigned short* __restrict__ vtb,
                                                      const float* __restrict__ sim,
                                                      const float* __restrict__ swl,
                                                      unsigned short* __restrict__ aout) {
    int h = blockIdx.y, bb = blockIdx.z;
    int n0 = blockIdx.x * 128;
    int tid = threadIdx.x;
    int w = tid >> 6, lane = tid & 63;
    int lrow = lane & 15, quad = lane >> 4;
    const unsigned short* q = qb + ((size_t)(bb * Hh + h)) * Nn * HD;
    const unsigned short* k = kb + ((size_t)(bb * Hh + h)) * Nn * HD;
    const unsigned short* vt = vtb + ((size_t)(bb * Hh + h)) * HD * Nn;
    float alpha = 1.f / (1.f + __expf(-swl[0]));
    float c1 = (1.f - alpha) * SCALE * LOG2E;   // exp2-folded
    float a2 = alpha * LOG2E;                    // exp2-folded

    __shared__ unsigned short sK[2][8192];     // [2 halves][64 keys(pi-perm)][64 d]
    __shared__ unsigned short sV[2][8192];     // [2 halves][64 e][64 keys]

    int qr0 = n0 + w * 32;                     // wave owns 32 q-rows (g=2)
    bf16x8 qf[2][2];
    #pragma unroll
    for (int g = 0; g < 2; g++) {
        qf[g][0] = ldfrag(q + (size_t)(qr0 + g * 16 + lrow) * HD + quad * 8);
        qf[g][1] = ldfrag(q + (size_t)(qr0 + g * 16 + lrow) * HD + 32 + quad * 8);
    }

    f32x4 o[2][4];
    #pragma unroll
    for (int g = 0; g < 2; g++)
        #pragma unroll
        for (int et = 0; et < 4; et++) o[g][et] = (f32x4){0.f, 0.f, 0.f, 0.f};
    float rsum[2] = {0.f, 0.f};

    int bs0 = (quad + (lrow >> 1)) & 7;
    int bs1 = (4 + quad + (lrow >> 1)) & 7;

    // sim base: lane's keys at sub-tile ks are mbase + koff(ks) + quad*8 + r
    const float* gS0 = sim + (size_t)(qr0 + lrow) * Nn + quad * 8;
    const float* gS1 = gS0 + (size_t)16 * Nn;

    // staging precompute (per 64-key half): LDS row rho; K source row pi(rho)
    int rowA = tid >> 3, rowB = (256 + tid) >> 3;
    int cgA = ((tid & 7) - (rowA >> 1)) & 7;
    int cgB = ((tid & 7) - (rowB >> 1)) & 7;   // (256+tid)&7 == tid&7
    int growA = ((rowA & 28) << 1) | ((rowA & 32) >> 3) | (rowA & 3);
    int growB = ((rowB & 28) << 1) | ((rowB & 32) >> 3) | (rowB & 3);

    // prologue: stage tile 0 (both halves), load sim(0, half0)
    STAGE(0, 0);
    float4 sm[4][2], smN[4][2];
    SIMLOAD(sm, 0);
    __syncthreads();

    for (int t = 0; t < 8; t++) {
        int cur = t & 1;
        int m0 = t * 128;

        if (t < 7) STAGE(cur ^ 1, m0 + 128);   // next 128-key tile, both halves
        SIMLOAD(smN, m0 + 64);                 // half1 sim (covered by half0 compute)

        HALF_COMPUTE(&sK[cur][0], &sV[cur][0]);          // half 0

        #pragma unroll
        for (int ks = 0; ks < 4; ks++) { sm[ks][0] = smN[ks][0]; sm[ks][1] = smN[ks][1]; }
        if (t < 7) SIMLOAD(smN, m0 + 128);     // next-iter half0 sim

        HALF_COMPUTE(&sK[cur][4096], &sV[cur][4096]);    // half 1

        #pragma unroll
        for (int ks = 0; ks < 4; ks++) { sm[ks][0] = smN[ks][0]; sm[ks][1] = smN[ks][1]; }
        __syncthreads();   // drains vmcnt: next tile staged
    }

    #pragma unroll
    for (int g = 0; g < 2; g++) {
        rsum[g] += __shfl_xor(rsum[g], 16);
        rsum[g] += __shfl_xor(rsum[g], 32);
    }

    #pragma unroll
    for (int g = 0; g < 2; g++)
        #pragma unroll
        for (int r = 0; r < 4; r++) {
            float inv = 1.f / __shfl(rsum[g], quad * 4 + r);
            int qn = qr0 + g * 16 + quad * 4 + r;
            #pragma unroll
            for (int et = 0; et < 4; et++)
                aout[((size_t)bb * Nn + qn) * Dd + h * HD + et * 16 + lrow]
                    = f2bf(o[g][et][r] * inv);
        }
}

extern "C" void kernel_launch(void* const* d_in, const int* in_sizes, int n_in,
                              void* d_out, int out_size, void* d_ws, size_t ws_size,
                              hipStream_t stream) {
    const float* x      = (const float*)d_in[0];
    const float* gamma  = (const float*)d_in[1];
    const float* beta   = (const float*)d_in[2];
    const float* w_qkv  = (const float*)d_in[3];
    const float* w_proj = (const float*)d_in[4];
    const float* b_proj = (const float*)d_in[5];
    const float* swl    = (const float*)d_in[6];
    const float* sim    = (const float*)d_in[7];
    float* out = (float*)d_out;

    unsigned short* ws = (unsigned short*)d_ws;
    unsigned short* xn     = ws;                  // 4096*1024
    unsigned short* wqkvT  = xn + 4194304;        // 3072*1024
    unsigned short* wprojT = wqkvT + 3145728;     // 1024*1024
    unsigned short* qb     = wprojT + 1048576;    // 4*16*1024*64
    unsigned short* kb     = qb + 4194304;
    unsigned short* vtb    = kb + 4194304;
    unsigned short* aout   = vtb + 4194304;       // 4096*1024
    // total 24M shorts = 48 MB

    prep_kernel<<<8192, 256, 0, stream>>>(x, gamma, beta, xn, w_qkv, wqkvT, w_proj, wprojT);
    gemm_qkv<<<dim3(24, 32), 256, 0, stream>>>(xn, wqkvT, qb, kb, vtb);
    attn_kernel<<<dim3(8, 16, 4), 256, 0, stream>>>(qb, kb, vtb, sim, swl, aout);
    gemm_proj<<<dim3(8, 32), 512, 0, stream>>>(aout, wprojT, b_proj, x, out);
}

// Round 13
// 194.287 us; speedup vs baseline: 1.0225x; 1.0225x over previous
//
#include <hip/hip_runtime.h>

#define Bz 4
#define Nn 1024
#define Dd 1024
#define Hh 16
#define HD 64
#define SCALE 0.125f
#define LN_EPS 1e-5f

typedef __attribute__((ext_vector_type(8))) __bf16 bf16x8;
typedef __attribute__((ext_vector_type(4))) float f32x4;
typedef __attribute__((ext_vector_type(4))) unsigned int uint4v;

static __device__ inline unsigned short f2bf(float f) {
    unsigned int u = __float_as_uint(f);
    u += 0x7fffu + ((u >> 16) & 1u);   // round-to-nearest-even
    return (unsigned short)(u >> 16);
}

static __device__ inline bf16x8 ldfrag(const unsigned short* p) {
    return *(const bf16x8*)p;
}

static __device__ __forceinline__ void glds16(const unsigned short* g, unsigned short* l) {
    __builtin_amdgcn_global_load_lds((const __attribute__((address_space(1))) void*)g,
                                     (__attribute__((address_space(3))) void*)l, 16, 0, 0);
}

// ===== prep: LN (blocks 0..4095) + transpose w_qkv (4096..7167) +
//             transpose w_proj (7168..8191), all 256-thread blocks ==========
__global__ __launch_bounds__(256) void prep_kernel(const float* __restrict__ x,
                                                   const float* __restrict__ gamma,
                                                   const float* __restrict__ beta,
                                                   unsigned short* __restrict__ xn,
                                                   const float* __restrict__ w_qkv,
                                                   unsigned short* __restrict__ wqkvT,
                                                   const float* __restrict__ w_proj,
                                                   unsigned short* __restrict__ wprojT) {
    __shared__ float tile[32][33];
    int blk = blockIdx.x;
    int tid = threadIdx.x;

    if (blk < 4096) {
        // -------- LayerNorm row --------
        const float* xr = x + (size_t)blk * Dd;
        float4 v = ((const float4*)xr)[tid];
        float s = v.x + v.y + v.z + v.w;
        float ss = v.x * v.x + v.y * v.y + v.z * v.z + v.w * v.w;
        for (int o = 32; o > 0; o >>= 1) {
            s += __shfl_down(s, o);
            ss += __shfl_down(ss, o);
        }
        float* red = &tile[0][0];
        int wid = tid >> 6;
        if ((tid & 63) == 0) { red[wid * 2] = s; red[wid * 2 + 1] = ss; }
        __syncthreads();
        float tot = red[0] + red[2] + red[4] + red[6];
        float tot2 = red[1] + red[3] + red[5] + red[7];
        float mu = tot * (1.0f / Dd);
        float var = tot2 * (1.0f / Dd) - mu * mu;
        float inv = rsqrtf(var + LN_EPS);
        float4 g = ((const float4*)gamma)[tid];
        float4 b = ((const float4*)beta)[tid];
        ushort4 o4;
        o4.x = f2bf((v.x - mu) * inv * g.x + b.x);
        o4.y = f2bf((v.y - mu) * inv * g.y + b.y);
        o4.z = f2bf((v.z - mu) * inv * g.z + b.z);
        o4.w = f2bf((v.w - mu) * inv * g.w + b.w);
        ((ushort4*)(xn + (size_t)blk * Dd))[tid] = o4;
    } else {
        // -------- weight transpose fp32 [rows][cols] -> bf16 [cols][rows] ----
        const float* in;
        unsigned short* out;
        int cols, c0, r0;
        if (blk < 7168) {
            int idx = blk - 4096;            // 96 x-tiles, 32 y-tiles
            in = w_qkv; out = wqkvT; cols = 3072;
            c0 = (idx % 96) * 32; r0 = (idx / 96) * 32;
        } else {
            int idx = blk - 7168;            // 32 x 32 tiles
            in = w_proj; out = wprojT; cols = 1024;
            c0 = (idx % 32) * 32; r0 = (idx / 32) * 32;
        }
        int tx = tid & 31, ty = tid >> 5;    // 32 x 8
        #pragma unroll
        for (int i = 0; i < 32; i += 8)
            tile[ty + i][tx] = in[(size_t)(r0 + ty + i) * cols + c0 + tx];
        __syncthreads();
        #pragma unroll
        for (int i = 0; i < 32; i += 8)
            out[(size_t)(c0 + ty + i) * 1024 + r0 + tx] = f2bf(tile[tx][ty + i]);
    }
}

// ---- QKV GEMM v2 (r14): xn[4096][1024] @ wqkvT[3072][1024] -> q/k/vt ------
// Was: 256 thr / 4 waves, barrier->stage->barrier (staging latency exposed).
// Now: 512 thr / 8 waves (2M x 4N, 64x32 per wave), 2-phase dbuf: stage(t+1)
// issued BEFORE compute(t), ONE barrier/iter. Same tile, same K order =>
// bit-identical results. LDS 64KB (2 blocks/CU resident, grid 3/CU queues).
__global__ __launch_bounds__(512, 2) void gemm_qkv(const unsigned short* __restrict__ A,
                                                   const unsigned short* __restrict__ Bt,
                                                   unsigned short* __restrict__ qb,
                                                   unsigned short* __restrict__ kb,
                                                   unsigned short* __restrict__ vtb) {
    __shared__ unsigned short sA[2][8192], sB[2][8192];
    int tid = threadIdx.x;
    int w = tid >> 6, lane = tid & 63, lrow = lane & 15, quad = lane >> 4;
    int wm = w >> 2, wn = w & 3;           // 2 x 4 wave grid
    int rowbase = blockIdx.y * 128;
    int colbase = blockIdx.x * 128;

    // staging: 512 threads x 2 chunks cover each 128x64 tile (1024 chunks)
    int srow = tid >> 3;                   // rows 0-63; +64 for 2nd chunk
    int gch = ((tid & 7) - (srow >> 1)) & 7;
    const unsigned short* gA = A + (size_t)(rowbase + srow) * 1024 + gch * 8;
    const unsigned short* gB = Bt + (size_t)(colbase + srow) * 1024 + gch * 8;

    int bs0 = ((quad + (lrow >> 1)) & 7) * 8;
    int bs1 = ((4 + quad + (lrow >> 1)) & 7) * 8;

    f32x4 acc[4][2];
    #pragma unroll
    for (int i = 0; i < 4; i++)
        #pragma unroll
        for (int j = 0; j < 2; j++)
            acc[i][j] = (f32x4){0.f, 0.f, 0.f, 0.f};

    // prologue: stage k-tile 0 into buffer 0
    glds16(gA, &sA[0][0] + w * 512);
    glds16(gA + (size_t)64 * 1024, &sA[0][0] + 4096 + w * 512);
    glds16(gB, &sB[0][0] + w * 512);
    glds16(gB + (size_t)64 * 1024, &sB[0][0] + 4096 + w * 512);
    __syncthreads();

    for (int t = 0; t < 16; t++) {
        int cur = t & 1;
        if (t < 15) {
            // issue next k-tile staging BEFORE compute (overlaps with MFMA)
            int k1 = (t + 1) * 64;
            glds16(gA + k1, &sA[cur ^ 1][0] + w * 512);
            glds16(gA + (size_t)64 * 1024 + k1, &sA[cur ^ 1][0] + 4096 + w * 512);
            glds16(gB + k1, &sB[cur ^ 1][0] + w * 512);
            glds16(gB + (size_t)64 * 1024 + k1, &sB[cur ^ 1][0] + 4096 + w * 512);
        }

        const unsigned short* fa = &sA[cur][0] + (wm * 64 + lrow) * 64;
        const unsigned short* fb = &sB[cur][0] + (wn * 32 + lrow) * 64;
        #pragma unroll
        for (int s = 0; s < 2; s++) {
            int bo = s ? bs1 : bs0;
            bf16x8 a[4], b[2];
            #pragma unroll
            for (int i = 0; i < 4; i++) a[i] = *(const bf16x8*)(fa + i * 1024 + bo);
            #pragma unroll
            for (int j = 0; j < 2; j++) b[j] = *(const bf16x8*)(fb + j * 1024 + bo);
            #pragma unroll
            for (int i = 0; i < 4; i++)
                #pragma unroll
                for (int j = 0; j < 2; j++)
                    acc[i][j] = __builtin_amdgcn_mfma_f32_16x16x32_bf16(a[i], b[j], acc[i][j], 0, 0, 0);
        }

        __syncthreads();   // drains staging(t+1); all waves done with buf[cur]
    }

    if (colbase < 2048) {
        // q/k columns: e-contiguous scalar stores
        #pragma unroll
        for (int j = 0; j < 2; j++) {
            int col = colbase + wn * 32 + j * 16 + lrow;
            int s = col >> 10, rem = col & 1023;
            int h = rem >> 6, e = rem & 63;
            unsigned short* dst = (s == 0) ? qb : kb;
            #pragma unroll
            for (int i = 0; i < 4; i++) {
                #pragma unroll
                for (int r = 0; r < 4; r++) {
                    int R = rowbase + wm * 64 + i * 16 + quad * 4 + r;
                    int bb = R >> 10, n = R & 1023;
                    dst[(((size_t)(bb * Hh + h)) * Nn + n) * HD + e] = f2bf(acc[i][j][r]);
                }
            }
        }
    } else {
        // v columns: transpose 64x32 wave tile through LDS -> b64 n-contiguous
        int bb = rowbase >> 10;
        int nbase = (rowbase & 1023) + wm * 64;
        unsigned short* sc = &sA[0][0] + w * 2048;   // per-wave scratch [16][68]
        int er = lane >> 2, nc = lane & 3;
        #pragma unroll
        for (int j = 0; j < 2; j++) {
            __syncthreads();
            int ebase = colbase + wn * 32 + j * 16 - 2048;
            int h = ebase >> 6, e0 = ebase & 63;
            #pragma unroll
            for (int i = 0; i < 4; i++) {
                uint2 pk;
                pk.x = (unsigned)f2bf(acc[i][j][0]) | ((unsigned)f2bf(acc[i][j][1]) << 16);
                pk.y = (unsigned)f2bf(acc[i][j][2]) | ((unsigned)f2bf(acc[i][j][3]) << 16);
                *(uint2*)(sc + lrow * 68 + i * 16 + quad * 4) = pk;
            }
            __syncthreads();
            unsigned short* vrow = vtb + ((size_t)((bb * Hh + h) * HD) + e0 + er) * Nn + nbase;
            #pragma unroll
            for (int c = 0; c < 4; c++) {
                uint2 v = *(const uint2*)(sc + er * 68 + c * 16 + nc * 4);
                *(uint2*)(vrow + c * 16 + nc * 4) = v;
            }
        }
    }
}

// ---- proj GEMM v2 (r12): aout[4096][1024] @ wprojT[1024][1024] + bias + x --
// 512 thr / 8 waves (2M x 4N, 64x32 per wave) => 2 waves/SIMD, 2-phase dbuf
// (stage(t+1) issued BEFORE compute(t), ONE barrier/iter).
__global__ __launch_bounds__(512, 2) void gemm_proj(const unsigned short* __restrict__ A,
                                                    const unsigned short* __restrict__ Bt,
                                                    const float* __restrict__ bias,
                                                    const float* __restrict__ x,
                                                    float* __restrict__ out) {
    __shared__ unsigned short sA[2][8192], sB[2][8192];
    int tid = threadIdx.x;
    int w = tid >> 6, lane = tid & 63, lrow = lane & 15, quad = lane >> 4;
    int wm = w >> 2, wn = w & 3;           // 2 x 4 wave grid
    int rowbase = blockIdx.y * 128;
    int colbase = blockIdx.x * 128;

    int srow = tid >> 3;
    int gch = ((tid & 7) - (srow >> 1)) & 7;
    const unsigned short* gA = A + (size_t)(rowbase + srow) * 1024 + gch * 8;
    const unsigned short* gB = Bt + (size_t)(colbase + srow) * 1024 + gch * 8;

    int bs0 = ((quad + (lrow >> 1)) & 7) * 8;
    int bs1 = ((4 + quad + (lrow >> 1)) & 7) * 8;

    f32x4 acc[4][2];
    #pragma unroll
    for (int i = 0; i < 4; i++)
        #pragma unroll
        for (int j = 0; j < 2; j++)
            acc[i][j] = (f32x4){0.f, 0.f, 0.f, 0.f};

    glds16(gA, &sA[0][0] + w * 512);
    glds16(gA + (size_t)64 * 1024, &sA[0][0] + 4096 + w * 512);
    glds16(gB, &sB[0][0] + w * 512);
    glds16(gB + (size_t)64 * 1024, &sB[0][0] + 4096 + w * 512);
    __syncthreads();

    for (int t = 0; t < 16; t++) {
        int cur = t & 1;
        if (t < 15) {
            int k1 = (t + 1) * 64;
            glds16(gA + k1, &sA[cur ^ 1][0] + w * 512);
            glds16(gA + (size_t)64 * 1024 + k1, &sA[cur ^ 1][0] + 4096 + w * 512);
            glds16(gB + k1, &sB[cur ^ 1][0] + w * 512);
            glds16(gB + (size_t)64 * 1024 + k1, &sB[cur ^ 1][0] + 4096 + w * 512);
        }

        const unsigned short* fa = &sA[cur][0] + (wm * 64 + lrow) * 64;
        const unsigned short* fb = &sB[cur][0] + (wn * 32 + lrow) * 64;
        #pragma unroll
        for (int s = 0; s < 2; s++) {
            int bo = s ? bs1 : bs0;
            bf16x8 a[4], b[2];
            #pragma unroll
            for (int i = 0; i < 4; i++) a[i] = *(const bf16x8*)(fa + i * 1024 + bo);
            #pragma unroll
            for (int j = 0; j < 2; j++) b[j] = *(const bf16x8*)(fb + j * 1024 + bo);
            #pragma unroll
            for (int i = 0; i < 4; i++)
                #pragma unroll
                for (int j = 0; j < 2; j++)
                    acc[i][j] = __builtin_amdgcn_mfma_f32_16x16x32_bf16(a[i], b[j], acc[i][j], 0, 0, 0);
        }

        __syncthreads();
    }

    #pragma unroll
    for (int j = 0; j < 2; j++) {
        int col = colbase + wn * 32 + j * 16 + lrow;
        float bc = bias[col];
        #pragma unroll
        for (int i = 0; i < 4; i++) {
            #pragma unroll
            for (int r = 0; r < 4; r++) {
                int R = rowbase + wm * 64 + i * 16 + quad * 4 + r;
                out[(size_t)R * 1024 + col] = acc[i][j][r] + bc + x[(size_t)R * 1024 + col];
            }
        }
    }
}

// ============ fused attention v8 (r11, reinstated r14): P-in-register ======
// K rows staged into LDS bit-permuted: LDS row rho holds global key
//   pi(rho) = rho[4]<<5 | rho[3:2]<<3 | rho[5]<<2 | rho[1:0]
// => lane's QK outputs ARE its PV A-frag: A-frag[ms] = {pk[ms], pk[ms+2]}
// from its OWN registers. No sP. dbuf K/V, 1 barrier/iter. 48.0us measured;
// structural floor confirmed across 5 variants (r6-r13) — parked.
#define LOG2E 1.4426950408889634f
__global__ __launch_bounds__(256, 2) void attn_kernel(const unsigned short* __restrict__ qb,
                                                      const unsigned short* __restrict__ kb,
                                                      const unsigned short* __restrict__ vtb,
                                                      const float* __restrict__ sim,
                                                      const float* __restrict__ swl,
                                                      unsigned short* __restrict__ aout) {
    int h = blockIdx.y, bb = blockIdx.z;
    int n0 = blockIdx.x * 128;
    int tid = threadIdx.x;
    int w = tid >> 6, lane = tid & 63;
    int lrow = lane & 15, quad = lane >> 4;
    const unsigned short* q = qb + ((size_t)(bb * Hh + h)) * Nn * HD;
    const unsigned short* k = kb + ((size_t)(bb * Hh + h)) * Nn * HD;
    const unsigned short* vt = vtb + ((size_t)(bb * Hh + h)) * HD * Nn;
    float alpha = 1.f / (1.f + __expf(-swl[0]));
    float c1 = (1.f - alpha) * SCALE * LOG2E;   // exp2-folded
    float a2 = alpha * LOG2E;                    // exp2-folded

    __shared__ unsigned short sK[2][4096];     // [64 keys(pi-permuted)][64 d]
    __shared__ unsigned short sV[2][4096];     // [64 e][64 keys], chunk-swizzled

    int qr0 = n0 + w * 32;                     // wave owns 32 q-rows (g=2)
    bf16x8 qf[2][2];
    #pragma unroll
    for (int g = 0; g < 2; g++) {
        qf[g][0] = ldfrag(q + (size_t)(qr0 + g * 16 + lrow) * HD + quad * 8);
        qf[g][1] = ldfrag(q + (size_t)(qr0 + g * 16 + lrow) * HD + 32 + quad * 8);
    }

    f32x4 o[2][4];
    #pragma unroll
    for (int g = 0; g < 2; g++)
        #pragma unroll
        for (int et = 0; et < 4; et++) o[g][et] = (f32x4){0.f, 0.f, 0.f, 0.f};
    float rsum[2] = {0.f, 0.f};

    int bs0 = (quad + (lrow >> 1)) & 7;
    int bs1 = (4 + quad + (lrow >> 1)) & 7;

    // sim base: lane's keys at tile ks are m0 + koff(ks) + quad*8 + r
    const float* gS0 = sim + (size_t)(qr0 + lrow) * Nn + quad * 8;
    const float* gS1 = gS0 + (size_t)16 * Nn;

    // staging precompute: LDS row rho; K source row pi(rho); V row rho.
    int rowA = tid >> 3, rowB = (256 + tid) >> 3;
    int cgA = ((tid & 7) - (rowA >> 1)) & 7;
    int cgB = ((tid & 7) - (rowB >> 1)) & 7;
    int growA = ((rowA & 28) << 1) | ((rowA & 32) >> 3) | (rowA & 3);
    int growB = ((rowB & 28) << 1) | ((rowB & 32) >> 3) | (rowB & 3);

    // prologue: stage K/V tile 0, load sim tile 0
    glds16(k + (size_t)growA * HD + cgA * 8, &sK[0][0] + w * 512);
    glds16(k + (size_t)growB * HD + cgB * 8, &sK[0][0] + 2048 + w * 512);
    glds16(vt + (size_t)rowA * Nn + cgA * 8, &sV[0][0] + w * 512);
    glds16(vt + (size_t)rowB * Nn + cgB * 8, &sV[0][0] + 2048 + w * 512);
    float4 sm[4][2];
    #pragma unroll
    for (int ks = 0; ks < 4; ks++) {
        int koff = ((ks & 1) << 5) | ((ks >> 1) << 2);
        sm[ks][0] = *(const float4*)(gS0 + koff);
        sm[ks][1] = *(const float4*)(gS1 + koff);
    }
    __syncthreads();

    for (int t = 0; t < 16; t++) {
        int cur = t & 1;
        float4 smN[4][2];
        if (t < 15) {
            int m1 = (t + 1) * 64;
            unsigned short* dK = &sK[cur ^ 1][0];
            unsigned short* dV = &sV[cur ^ 1][0];
            glds16(k + (size_t)(m1 + growA) * HD + cgA * 8, dK + w * 512);
            glds16(k + (size_t)(m1 + growB) * HD + cgB * 8, dK + 2048 + w * 512);
            glds16(vt + (size_t)rowA * Nn + m1 + cgA * 8, dV + w * 512);
            glds16(vt + (size_t)rowB * Nn + m1 + cgB * 8, dV + 2048 + w * 512);
            #pragma unroll
            for (int ks = 0; ks < 4; ks++) {
                int koff = ((ks & 1) << 5) | ((ks >> 1) << 2);
                smN[ks][0] = *(const float4*)(gS0 + m1 + koff);
                smN[ks][1] = *(const float4*)(gS1 + m1 + koff);
            }
        }

        const unsigned short* sKc = sK[cur];
        const unsigned short* sVc = sV[cur];
        uint2 pk[2][4];                        // [g][ks] packed bf16 P
        #pragma unroll
        for (int ks = 0; ks < 4; ks++) {
            const unsigned short* kr = sKc + (ks * 16 + lrow) * 64;
            bf16x8 ak0 = *(const bf16x8*)(kr + bs0 * 8);
            bf16x8 ak1 = *(const bf16x8*)(kr + bs1 * 8);
            #pragma unroll
            for (int g = 0; g < 2; g++) {
                f32x4 c = (f32x4){0.f, 0.f, 0.f, 0.f};
                c = __builtin_amdgcn_mfma_f32_16x16x32_bf16(ak0, qf[g][0], c, 0, 0, 0);
                c = __builtin_amdgcn_mfma_f32_16x16x32_bf16(ak1, qf[g][1], c, 0, 0, 0);
                float e0 = __builtin_amdgcn_exp2f(c1 * c[0] + a2 * sm[ks][g].x);
                float e1 = __builtin_amdgcn_exp2f(c1 * c[1] + a2 * sm[ks][g].y);
                float e2 = __builtin_amdgcn_exp2f(c1 * c[2] + a2 * sm[ks][g].z);
                float e3 = __builtin_amdgcn_exp2f(c1 * c[3] + a2 * sm[ks][g].w);
                rsum[g] += (e0 + e1) + (e2 + e3);
                pk[g][ks].x = (__float_as_uint(e0) >> 16) | (__float_as_uint(e1) & 0xffff0000u);
                pk[g][ks].y = (__float_as_uint(e2) >> 16) | (__float_as_uint(e3) & 0xffff0000u);
            }
        }

        __builtin_amdgcn_s_setprio(1);
        #pragma unroll
        for (int ms = 0; ms < 2; ms++) {
            bf16x8 pa[2];
            #pragma unroll
            for (int g = 0; g < 2; g++) {
                uint4v u;
                u.x = pk[g][ms].x;  u.y = pk[g][ms].y;
                u.z = pk[g][ms + 2].x;  u.w = pk[g][ms + 2].y;
                pa[g] = __builtin_bit_cast(bf16x8, u);
            }
            #pragma unroll
            for (int et = 0; et < 4; et++) {
                int e = et * 16 + lrow;
                int slot = (ms * 4 + quad + (e >> 1)) & 7;
                bf16x8 vb = *(const bf16x8*)(sVc + e * 64 + slot * 8);
                #pragma unroll
                for (int g = 0; g < 2; g++)
                    o[g][et] = __builtin_amdgcn_mfma_f32_16x16x32_bf16(pa[g], vb, o[g][et], 0, 0, 0);
            }
        }
        __builtin_amdgcn_s_setprio(0);

        __syncthreads();   // drains vmcnt: next K/V tiles staged, sim loaded
        if (t < 15) {
            #pragma unroll
            for (int ks = 0; ks < 4; ks++) {
                sm[ks][0] = smN[ks][0];
                sm[ks][1] = smN[ks][1];
            }
        }
    }

    #pragma unroll
    for (int g = 0; g < 2; g++) {
        rsum[g] += __shfl_xor(rsum[g], 16);
        rsum[g] += __shfl_xor(rsum[g], 32);
    }

    #pragma unroll
    for (int g = 0; g < 2; g++)
        #pragma unroll
        for (int r = 0; r < 4; r++) {
            float inv = 1.f / __shfl(rsum[g], quad * 4 + r);
            int qn = qr0 + g * 16 + quad * 4 + r;
            #pragma unroll
            for (int et = 0; et < 4; et++)
                aout[((size_t)bb * Nn + qn) * Dd + h * HD + et * 16 + lrow]
                    = f2bf(o[g][et][r] * inv);
        }
}

extern "C" void kernel_launch(void* const* d_in, const int* in_sizes, int n_in,
                              void* d_out, int out_size, void* d_ws, size_t ws_size,
                              hipStream_t stream) {
    const float* x      = (const float*)d_in[0];
    const float* gamma  = (const float*)d_in[1];
    const float* beta   = (const float*)d_in[2];
    const float* w_qkv  = (const float*)d_in[3];
    const float* w_proj = (const float*)d_in[4];
    const float* b_proj = (const float*)d_in[5];
    const float* swl    = (const float*)d_in[6];
    const float* sim    = (const float*)d_in[7];
    float* out = (float*)d_out;

    unsigned short* ws = (unsigned short*)d_ws;
    unsigned short* xn     = ws;                  // 4096*1024
    unsigned short* wqkvT  = xn + 4194304;        // 3072*1024
    unsigned short* wprojT = wqkvT + 3145728;     // 1024*1024
    unsigned short* qb     = wprojT + 1048576;    // 4*16*1024*64
    unsigned short* kb     = qb + 4194304;
    unsigned short* vtb    = kb + 4194304;
    unsigned short* aout   = vtb + 4194304;       // 4096*1024
    // total 24M shorts = 48 MB

    prep_kernel<<<8192, 256, 0, stream>>>(x, gamma, beta, xn, w_qkv, wqkvT, w_proj, wprojT);
    gemm_qkv<<<dim3(24, 32), 512, 0, stream>>>(xn, wqkvT, qb, kb, vtb);
    attn_kernel<<<dim3(8, 16, 4), 256, 0, stream>>>(qb, kb, vtb, sim, swl, aout);
    gemm_proj<<<dim3(8, 32), 512, 0, stream>>>(aout, wprojT, b_proj, x, out);
}

// Round 16
// 190.471 us; speedup vs baseline: 1.0430x; 1.0200x over previous
//
#include <hip/hip_runtime.h>

#define Bz 4
#define Nn 1024
#define Dd 1024
#define Hh 16
#define HD 64
#define SCALE 0.125f
#define LN_EPS 1e-5f

typedef __attribute__((ext_vector_type(8))) __bf16 bf16x8;
typedef __attribute__((ext_vector_type(4))) float f32x4;
typedef __attribute__((ext_vector_type(4))) unsigned int uint4v;

static __device__ inline unsigned short f2bf(float f) {
    unsigned int u = __float_as_uint(f);
    u += 0x7fffu + ((u >> 16) & 1u);   // round-to-nearest-even
    return (unsigned short)(u >> 16);
}

static __device__ inline bf16x8 ldfrag(const unsigned short* p) {
    return *(const bf16x8*)p;
}

static __device__ __forceinline__ void glds16(const unsigned short* g, unsigned short* l) {
    __builtin_amdgcn_global_load_lds((const __attribute__((address_space(1))) void*)g,
                                     (__attribute__((address_space(3))) void*)l, 16, 0, 0);
}

// ===== prep: LN (blocks 0..4095) + transpose w_qkv (4096..7167) +
//             transpose w_proj (7168..8191), all 256-thread blocks ==========
// r16: REVERTED to verified r14 version (r15's uint-wide write read
// tile[2*tx] with tx<32 -> OOB on [32][33] tile -> NaN. Widening retry must
// use tx in [0,16) x 2 rows — queued separately, never bundled again).
__global__ __launch_bounds__(256) void prep_kernel(const float* __restrict__ x,
                                                   const float* __restrict__ gamma,
                                                   const float* __restrict__ beta,
                                                   unsigned short* __restrict__ xn,
                                                   const float* __restrict__ w_qkv,
                                                   unsigned short* __restrict__ wqkvT,
                                                   const float* __restrict__ w_proj,
                                                   unsigned short* __restrict__ wprojT) {
    __shared__ float tile[32][33];
    int blk = blockIdx.x;
    int tid = threadIdx.x;

    if (blk < 4096) {
        // -------- LayerNorm row --------
        const float* xr = x + (size_t)blk * Dd;
        float4 v = ((const float4*)xr)[tid];
        float s = v.x + v.y + v.z + v.w;
        float ss = v.x * v.x + v.y * v.y + v.z * v.z + v.w * v.w;
        for (int o = 32; o > 0; o >>= 1) {
            s += __shfl_down(s, o);
            ss += __shfl_down(ss, o);
        }
        float* red = &tile[0][0];
        int wid = tid >> 6;
        if ((tid & 63) == 0) { red[wid * 2] = s; red[wid * 2 + 1] = ss; }
        __syncthreads();
        float tot = red[0] + red[2] + red[4] + red[6];
        float tot2 = red[1] + red[3] + red[5] + red[7];
        float mu = tot * (1.0f / Dd);
        float var = tot2 * (1.0f / Dd) - mu * mu;
        float inv = rsqrtf(var + LN_EPS);
        float4 g = ((const float4*)gamma)[tid];
        float4 b = ((const float4*)beta)[tid];
        ushort4 o4;
        o4.x = f2bf((v.x - mu) * inv * g.x + b.x);
        o4.y = f2bf((v.y - mu) * inv * g.y + b.y);
        o4.z = f2bf((v.z - mu) * inv * g.z + b.z);
        o4.w = f2bf((v.w - mu) * inv * g.w + b.w);
        ((ushort4*)(xn + (size_t)blk * Dd))[tid] = o4;
    } else {
        // -------- weight transpose fp32 [rows][cols] -> bf16 [cols][rows] ----
        const float* in;
        unsigned short* out;
        int cols, c0, r0;
        if (blk < 7168) {
            int idx = blk - 4096;            // 96 x-tiles, 32 y-tiles
            in = w_qkv; out = wqkvT; cols = 3072;
            c0 = (idx % 96) * 32; r0 = (idx / 96) * 32;
        } else {
            int idx = blk - 7168;            // 32 x 32 tiles
            in = w_proj; out = wprojT; cols = 1024;
            c0 = (idx % 32) * 32; r0 = (idx / 32) * 32;
        }
        int tx = tid & 31, ty = tid >> 5;    // 32 x 8
        #pragma unroll
        for (int i = 0; i < 32; i += 8)
            tile[ty + i][tx] = in[(size_t)(r0 + ty + i) * cols + c0 + tx];
        __syncthreads();
        #pragma unroll
        for (int i = 0; i < 32; i += 8)
            out[(size_t)(c0 + ty + i) * 1024 + r0 + tx] = f2bf(tile[tx][ty + i]);
    }
}

// ---- QKV GEMM v2 (r14): xn[4096][1024] @ wqkvT[3072][1024] -> q/k/vt ------
// 512 thr / 8 waves (2M x 4N, 64x32 per wave), 2-phase dbuf: stage(t+1)
// issued BEFORE compute(t), ONE barrier/iter. Verified r14 (passed, absmax=).
__global__ __launch_bounds__(512, 2) void gemm_qkv(const unsigned short* __restrict__ A,
                                                   const unsigned short* __restrict__ Bt,
                                                   unsigned short* __restrict__ qb,
                                                   unsigned short* __restrict__ kb,
                                                   unsigned short* __restrict__ vtb) {
    __shared__ unsigned short sA[2][8192], sB[2][8192];
    int tid = threadIdx.x;
    int w = tid >> 6, lane = tid & 63, lrow = lane & 15, quad = lane >> 4;
    int wm = w >> 2, wn = w & 3;           // 2 x 4 wave grid
    int rowbase = blockIdx.y * 128;
    int colbase = blockIdx.x * 128;

    // staging: 512 threads x 2 chunks cover each 128x64 tile (1024 chunks)
    int srow = tid >> 3;                   // rows 0-63; +64 for 2nd chunk
    int gch = ((tid & 7) - (srow >> 1)) & 7;
    const unsigned short* gA = A + (size_t)(rowbase + srow) * 1024 + gch * 8;
    const unsigned short* gB = Bt + (size_t)(colbase + srow) * 1024 + gch * 8;

    int bs0 = ((quad + (lrow >> 1)) & 7) * 8;
    int bs1 = ((4 + quad + (lrow >> 1)) & 7) * 8;

    f32x4 acc[4][2];
    #pragma unroll
    for (int i = 0; i < 4; i++)
        #pragma unroll
        for (int j = 0; j < 2; j++)
            acc[i][j] = (f32x4){0.f, 0.f, 0.f, 0.f};

    // prologue: stage k-tile 0 into buffer 0
    glds16(gA, &sA[0][0] + w * 512);
    glds16(gA + (size_t)64 * 1024, &sA[0][0] + 4096 + w * 512);
    glds16(gB, &sB[0][0] + w * 512);
    glds16(gB + (size_t)64 * 1024, &sB[0][0] + 4096 + w * 512);
    __syncthreads();

    for (int t = 0; t < 16; t++) {
        int cur = t & 1;
        if (t < 15) {
            // issue next k-tile staging BEFORE compute (overlaps with MFMA)
            int k1 = (t + 1) * 64;
            glds16(gA + k1, &sA[cur ^ 1][0] + w * 512);
            glds16(gA + (size_t)64 * 1024 + k1, &sA[cur ^ 1][0] + 4096 + w * 512);
            glds16(gB + k1, &sB[cur ^ 1][0] + w * 512);
            glds16(gB + (size_t)64 * 1024 + k1, &sB[cur ^ 1][0] + 4096 + w * 512);
        }

        const unsigned short* fa = &sA[cur][0] + (wm * 64 + lrow) * 64;
        const unsigned short* fb = &sB[cur][0] + (wn * 32 + lrow) * 64;
        #pragma unroll
        for (int s = 0; s < 2; s++) {
            int bo = s ? bs1 : bs0;
            bf16x8 a[4], b[2];
            #pragma unroll
            for (int i = 0; i < 4; i++) a[i] = *(const bf16x8*)(fa + i * 1024 + bo);
            #pragma unroll
            for (int j = 0; j < 2; j++) b[j] = *(const bf16x8*)(fb + j * 1024 + bo);
            #pragma unroll
            for (int i = 0; i < 4; i++)
                #pragma unroll
                for (int j = 0; j < 2; j++)
                    acc[i][j] = __builtin_amdgcn_mfma_f32_16x16x32_bf16(a[i], b[j], acc[i][j], 0, 0, 0);
        }

        __syncthreads();   // drains staging(t+1); all waves done with buf[cur]
    }

    if (colbase < 2048) {
        // q/k columns: e-contiguous scalar stores
        #pragma unroll
        for (int j = 0; j < 2; j++) {
            int col = colbase + wn * 32 + j * 16 + lrow;
            int s = col >> 10, rem = col & 1023;
            int h = rem >> 6, e = rem & 63;
            unsigned short* dst = (s == 0) ? qb : kb;
            #pragma unroll
            for (int i = 0; i < 4; i++) {
                #pragma unroll
                for (int r = 0; r < 4; r++) {
                    int R = rowbase + wm * 64 + i * 16 + quad * 4 + r;
                    int bb = R >> 10, n = R & 1023;
                    dst[(((size_t)(bb * Hh + h)) * Nn + n) * HD + e] = f2bf(acc[i][j][r]);
                }
            }
        }
    } else {
        // v columns: transpose 64x32 wave tile through LDS -> b64 n-contiguous
        int bb = rowbase >> 10;
        int nbase = (rowbase & 1023) + wm * 64;
        unsigned short* sc = &sA[0][0] + w * 2048;   // per-wave scratch [16][68]
        int er = lane >> 2, nc = lane & 3;
        #pragma unroll
        for (int j = 0; j < 2; j++) {
            __syncthreads();
            int ebase = colbase + wn * 32 + j * 16 - 2048;
            int h = ebase >> 6, e0 = ebase & 63;
            #pragma unroll
            for (int i = 0; i < 4; i++) {
                uint2 pk;
                pk.x = (unsigned)f2bf(acc[i][j][0]) | ((unsigned)f2bf(acc[i][j][1]) << 16);
                pk.y = (unsigned)f2bf(acc[i][j][2]) | ((unsigned)f2bf(acc[i][j][3]) << 16);
                *(uint2*)(sc + lrow * 68 + i * 16 + quad * 4) = pk;
            }
            __syncthreads();
            unsigned short* vrow = vtb + ((size_t)((bb * Hh + h) * HD) + e0 + er) * Nn + nbase;
            #pragma unroll
            for (int c = 0; c < 4; c++) {
                uint2 v = *(const uint2*)(sc + er * 68 + c * 16 + nc * 4);
                *(uint2*)(vrow + c * 16 + nc * 4) = v;
            }
        }
    }
}

// ---- proj GEMM v3 (r15, kept r16): 128x64 tile, grid (16,32) = 512 blocks -
// 2 blocks/CU (m114: two independent barrier groups overlap drain with the
// other block's compute). 256 thr / 4 waves (2M x 2N), 2-phase dbuf.
// Re-audited r16: staging phase 16c=0 mod 8 ok; frag/epilogue algebra ok.
__global__ __launch_bounds__(256, 2) void gemm_proj(const unsigned short* __restrict__ A,
                                                    const unsigned short* __restrict__ Bt,
                                                    const float* __restrict__ bias,
                                                    const float* __restrict__ x,
                                                    float* __restrict__ out) {
    __shared__ unsigned short sA[2][8192], sB[2][4096];
    int tid = threadIdx.x;
    int w = tid >> 6, lane = tid & 63, lrow = lane & 15, quad = lane >> 4;
    int wm = w >> 1, wn = w & 1;           // 2 x 2 wave grid
    int rowbase = blockIdx.y * 128;
    int colbase = blockIdx.x * 64;

    // staging: A tile 128x64 = 1024 chunks (4/thread); B tile 64x64 = 512 (2/thread)
    int srow = tid >> 3;                   // 0..31 base row; +32 per chunk c
    int gch = ((tid & 7) - (srow >> 1)) & 7;   // (c*32)>>1 = 16c ≡ 0 mod 8 -> same gch all c
    const unsigned short* gA = A + (size_t)(rowbase + srow) * 1024 + gch * 8;
    const unsigned short* gB = Bt + (size_t)(colbase + srow) * 1024 + gch * 8;

    int bs0 = ((quad + (lrow >> 1)) & 7) * 8;
    int bs1 = ((4 + quad + (lrow >> 1)) & 7) * 8;

    f32x4 acc[4][2];
    #pragma unroll
    for (int i = 0; i < 4; i++)
        #pragma unroll
        for (int j = 0; j < 2; j++)
            acc[i][j] = (f32x4){0.f, 0.f, 0.f, 0.f};

    // prologue: stage k-tile 0 into buffer 0
    #pragma unroll
    for (int c = 0; c < 4; c++)
        glds16(gA + (size_t)c * 32 * 1024, &sA[0][0] + c * 2048 + tid * 8);
    #pragma unroll
    for (int c = 0; c < 2; c++)
        glds16(gB + (size_t)c * 32 * 1024, &sB[0][0] + c * 2048 + tid * 8);
    __syncthreads();

    for (int t = 0; t < 16; t++) {
        int cur = t & 1;
        if (t < 15) {
            int k1 = (t + 1) * 64;
            #pragma unroll
            for (int c = 0; c < 4; c++)
                glds16(gA + (size_t)c * 32 * 1024 + k1, &sA[cur ^ 1][0] + c * 2048 + tid * 8);
            #pragma unroll
            for (int c = 0; c < 2; c++)
                glds16(gB + (size_t)c * 32 * 1024 + k1, &sB[cur ^ 1][0] + c * 2048 + tid * 8);
        }

        const unsigned short* fa = &sA[cur][0] + (wm * 64 + lrow) * 64;
        const unsigned short* fb = &sB[cur][0] + (wn * 32 + lrow) * 64;
        #pragma unroll
        for (int s = 0; s < 2; s++) {
            int bo = s ? bs1 : bs0;
            bf16x8 a[4], b[2];
            #pragma unroll
            for (int i = 0; i < 4; i++) a[i] = *(const bf16x8*)(fa + i * 1024 + bo);
            #pragma unroll
            for (int j = 0; j < 2; j++) b[j] = *(const bf16x8*)(fb + j * 1024 + bo);
            #pragma unroll
            for (int i = 0; i < 4; i++)
                #pragma unroll
                for (int j = 0; j < 2; j++)
                    acc[i][j] = __builtin_amdgcn_mfma_f32_16x16x32_bf16(a[i], b[j], acc[i][j], 0, 0, 0);
        }

        __syncthreads();
    }

    #pragma unroll
    for (int j = 0; j < 2; j++) {
        int col = colbase + wn * 32 + j * 16 + lrow;
        float bc = bias[col];
        #pragma unroll
        for (int i = 0; i < 4; i++) {
            #pragma unroll
            for (int r = 0; r < 4; r++) {
                int R = rowbase + wm * 64 + i * 16 + quad * 4 + r;
                out[(size_t)R * 1024 + col] = acc[i][j][r] + bc + x[(size_t)R * 1024 + col];
            }
        }
    }
}

// ============ fused attention v8 (r11): P-in-register via K-row permute ====
// 48.0us measured; structural floor confirmed across 5 variants — parked.
#define LOG2E 1.4426950408889634f
__global__ __launch_bounds__(256, 2) void attn_kernel(const unsigned short* __restrict__ qb,
                                                      const unsigned short* __restrict__ kb,
                                                      const unsigned short* __restrict__ vtb,
                                                      const float* __restrict__ sim,
                                                      const float* __restrict__ swl,
                                                      unsigned short* __restrict__ aout) {
    int h = blockIdx.y, bb = blockIdx.z;
    int n0 = blockIdx.x * 128;
    int tid = threadIdx.x;
    int w = tid >> 6, lane = tid & 63;
    int lrow = lane & 15, quad = lane >> 4;
    const unsigned short* q = qb + ((size_t)(bb * Hh + h)) * Nn * HD;
    const unsigned short* k = kb + ((size_t)(bb * Hh + h)) * Nn * HD;
    const unsigned short* vt = vtb + ((size_t)(bb * Hh + h)) * HD * Nn;
    float alpha = 1.f / (1.f + __expf(-swl[0]));
    float c1 = (1.f - alpha) * SCALE * LOG2E;   // exp2-folded
    float a2 = alpha * LOG2E;                    // exp2-folded

    __shared__ unsigned short sK[2][4096];     // [64 keys(pi-permuted)][64 d]
    __shared__ unsigned short sV[2][4096];     // [64 e][64 keys], chunk-swizzled

    int qr0 = n0 + w * 32;                     // wave owns 32 q-rows (g=2)
    bf16x8 qf[2][2];
    #pragma unroll
    for (int g = 0; g < 2; g++) {
        qf[g][0] = ldfrag(q + (size_t)(qr0 + g * 16 + lrow) * HD + quad * 8);
        qf[g][1] = ldfrag(q + (size_t)(qr0 + g * 16 + lrow) * HD + 32 + quad * 8);
    }

    f32x4 o[2][4];
    #pragma unroll
    for (int g = 0; g < 2; g++)
        #pragma unroll
        for (int et = 0; et < 4; et++) o[g][et] = (f32x4){0.f, 0.f, 0.f, 0.f};
    float rsum[2] = {0.f, 0.f};

    int bs0 = (quad + (lrow >> 1)) & 7;
    int bs1 = (4 + quad + (lrow >> 1)) & 7;

    // sim base: lane's keys at tile ks are m0 + koff(ks) + quad*8 + r
    const float* gS0 = sim + (size_t)(qr0 + lrow) * Nn + quad * 8;
    const float* gS1 = gS0 + (size_t)16 * Nn;

    // staging precompute: LDS row rho; K source row pi(rho); V row rho.
    int rowA = tid >> 3, rowB = (256 + tid) >> 3;
    int cgA = ((tid & 7) - (rowA >> 1)) & 7;
    int cgB = ((tid & 7) - (rowB >> 1)) & 7;
    int growA = ((rowA & 28) << 1) | ((rowA & 32) >> 3) | (rowA & 3);
    int growB = ((rowB & 28) << 1) | ((rowB & 32) >> 3) | (rowB & 3);

    // prologue: stage K/V tile 0, load sim tile 0
    glds16(k + (size_t)growA * HD + cgA * 8, &sK[0][0] + w * 512);
    glds16(k + (size_t)growB * HD + cgB * 8, &sK[0][0] + 2048 + w * 512);
    glds16(vt + (size_t)rowA * Nn + cgA * 8, &sV[0][0] + w * 512);
    glds16(vt + (size_t)rowB * Nn + cgB * 8, &sV[0][0] + 2048 + w * 512);
    float4 sm[4][2];
    #pragma unroll
    for (int ks = 0; ks < 4; ks++) {
        int koff = ((ks & 1) << 5) | ((ks >> 1) << 2);
        sm[ks][0] = *(const float4*)(gS0 + koff);
        sm[ks][1] = *(const float4*)(gS1 + koff);
    }
    __syncthreads();

    for (int t = 0; t < 16; t++) {
        int cur = t & 1;
        float4 smN[4][2];
        if (t < 15) {
            int m1 = (t + 1) * 64;
            unsigned short* dK = &sK[cur ^ 1][0];
            unsigned short* dV = &sV[cur ^ 1][0];
            glds16(k + (size_t)(m1 + growA) * HD + cgA * 8, dK + w * 512);
            glds16(k + (size_t)(m1 + growB) * HD + cgB * 8, dK + 2048 + w * 512);
            glds16(vt + (size_t)rowA * Nn + m1 + cgA * 8, dV + w * 512);
            glds16(vt + (size_t)rowB * Nn + m1 + cgB * 8, dV + 2048 + w * 512);
            #pragma unroll
            for (int ks = 0; ks < 4; ks++) {
                int koff = ((ks & 1) << 5) | ((ks >> 1) << 2);
                smN[ks][0] = *(const float4*)(gS0 + m1 + koff);
                smN[ks][1] = *(const float4*)(gS1 + m1 + koff);
            }
        }

        const unsigned short* sKc = sK[cur];
        const unsigned short* sVc = sV[cur];
        uint2 pk[2][4];                        // [g][ks] packed bf16 P
        #pragma unroll
        for (int ks = 0; ks < 4; ks++) {
            const unsigned short* kr = sKc + (ks * 16 + lrow) * 64;
            bf16x8 ak0 = *(const bf16x8*)(kr + bs0 * 8);
            bf16x8 ak1 = *(const bf16x8*)(kr + bs1 * 8);
            #pragma unroll
            for (int g = 0; g < 2; g++) {
                f32x4 c = (f32x4){0.f, 0.f, 0.f, 0.f};
                c = __builtin_amdgcn_mfma_f32_16x16x32_bf16(ak0, qf[g][0], c, 0, 0, 0);
                c = __builtin_amdgcn_mfma_f32_16x16x32_bf16(ak1, qf[g][1], c, 0, 0, 0);
                float e0 = __builtin_amdgcn_exp2f(c1 * c[0] + a2 * sm[ks][g].x);
                float e1 = __builtin_amdgcn_exp2f(c1 * c[1] + a2 * sm[ks][g].y);
                float e2 = __builtin_amdgcn_exp2f(c1 * c[2] + a2 * sm[ks][g].z);
                float e3 = __builtin_amdgcn_exp2f(c1 * c[3] + a2 * sm[ks][g].w);
                rsum[g] += (e0 + e1) + (e2 + e3);
                pk[g][ks].x = (__float_as_uint(e0) >> 16) | (__float_as_uint(e1) & 0xffff0000u);
                pk[g][ks].y = (__float_as_uint(e2) >> 16) | (__float_as_uint(e3) & 0xffff0000u);
            }
        }

        __builtin_amdgcn_s_setprio(1);
        #pragma unroll
        for (int ms = 0; ms < 2; ms++) {
            bf16x8 pa[2];
            #pragma unroll
            for (int g = 0; g < 2; g++) {
                uint4v u;
                u.x = pk[g][ms].x;  u.y = pk[g][ms].y;
                u.z = pk[g][ms + 2].x;  u.w = pk[g][ms + 2].y;
                pa[g] = __builtin_bit_cast(bf16x8, u);
            }
            #pragma unroll
            for (int et = 0; et < 4; et++) {
                int e = et * 16 + lrow;
                int slot = (ms * 4 + quad + (e >> 1)) & 7;
                bf16x8 vb = *(const bf16x8*)(sVc + e * 64 + slot * 8);
                #pragma unroll
                for (int g = 0; g < 2; g++)
                    o[g][et] = __builtin_amdgcn_mfma_f32_16x16x32_bf16(pa[g], vb, o[g][et], 0, 0, 0);
            }
        }
        __builtin_amdgcn_s_setprio(0);

        __syncthreads();   // drains vmcnt: next K/V tiles staged, sim loaded
        if (t < 15) {
            #pragma unroll
            for (int ks = 0; ks < 4; ks++) {
                sm[ks][0] = smN[ks][0];
                sm[ks][1] = smN[ks][1];
            }
        }
    }

    #pragma unroll
    for (int g = 0; g < 2; g++) {
        rsum[g] += __shfl_xor(rsum[g], 16);
        rsum[g] += __shfl_xor(rsum[g], 32);
    }

    #pragma unroll
    for (int g = 0; g < 2; g++)
        #pragma unroll
        for (int r = 0; r < 4; r++) {
            float inv = 1.f / __shfl(rsum[g], quad * 4 + r);
            int qn = qr0 + g * 16 + quad * 4 + r;
            #pragma unroll
            for (int et = 0; et < 4; et++)
                aout[((size_t)bb * Nn + qn) * Dd + h * HD + et * 16 + lrow]
                    = f2bf(o[g][et][r] * inv);
        }
}

extern "C" void kernel_launch(void* const* d_in, const int* in_sizes, int n_in,
                              void* d_out, int out_size, void* d_ws, size_t ws_size,
                              hipStream_t stream) {
    const float* x      = (const float*)d_in[0];
    const float* gamma  = (const float*)d_in[1];
    const float* beta   = (const float*)d_in[2];
    const float* w_qkv  = (const float*)d_in[3];
    const float* w_proj = (const float*)d_in[4];
    const float* b_proj = (const float*)d_in[5];
    const float* swl    = (const float*)d_in[6];
    const float* sim    = (const float*)d_in[7];
    float* out = (float*)d_out;

    unsigned short* ws = (unsigned short*)d_ws;
    unsigned short* xn     = ws;                  // 4096*1024
    unsigned short* wqkvT  = xn + 4194304;        // 3072*1024
    unsigned short* wprojT = wqkvT + 3145728;     // 1024*1024
    unsigned short* qb     = wprojT + 1048576;    // 4*16*1024*64
    unsigned short* kb     = qb + 4194304;
    unsigned short* vtb    = kb + 4194304;
    unsigned short* aout   = vtb + 4194304;       // 4096*1024
    // total 24M shorts = 48 MB

    prep_kernel<<<8192, 256, 0, stream>>>(x, gamma, beta, xn, w_qkv, wqkvT, w_proj, wprojT);
    gemm_qkv<<<dim3(24, 32), 512, 0, stream>>>(xn, wqkvT, qb, kb, vtb);
    attn_kernel<<<dim3(8, 16, 4), 256, 0, stream>>>(qb, kb, vtb, sim, swl, aout);
    gemm_proj<<<dim3(16, 32), 256, 0, stream>>>(aout, wprojT, b_proj, x, out);
}